// Round 1
// baseline (6186.714 us; speedup 1.0000x reference)
//
#include <hip/hip_runtime.h>
#include <hip/hip_bf16.h>
#include <cstdint>
#include <cmath>

#define T_TOK 4096
#define DIM   768
#define HEADS 12
#define HD    64
#define NEXP  8
#define FDIM  3072

__device__ __forceinline__ float gelu_tanh(float x) {
  // matches jax.nn.gelu(approximate=True)
  float u = 0.7978845608028654f * (x + 0.044715f * x * x * x);
  return 0.5f * x * (1.0f + tanhf(u));
}

// ---------------- generic tiled fp32 GEMM ----------------
// BM=128, BN=64, BK=16, 256 threads, 8x4 per-thread microtile.
// MODE 0: C = A@W + bias                     (dense rows)
// MODE 1: C = gelu(gather(A,perm)@W + bias)  (MoE up-proj, rows = expert tokens)
// MODE 2: atomicAdd(C[token], gate*(A@W + bias))  (MoE down-proj scatter)
#define BM 128
#define BN 64
#define BK 16

template<int MODE>
__global__ __launch_bounds__(256) void gemm_k(
    const float* __restrict__ A, const float* __restrict__ W,
    const float* __restrict__ bias, float* __restrict__ C,
    int M, int N, int K,
    const int* __restrict__ offsets, const int* __restrict__ perm,
    const float* __restrict__ gperm, int e)
{
  __shared__ float As[BK][BM + 4];
  __shared__ float Bs[BK][BN + 4];
  int start = 0;
  if (MODE > 0) { start = offsets[e]; M = offsets[e + 1] - start; }
  const int bm = blockIdx.y * BM;
  if (MODE > 0 && bm >= M) return;
  const int bn = blockIdx.x * BN;
  const int tid = threadIdx.x;
  const int tr = tid >> 4;   // 0..15 -> rows tr*8..tr*8+7
  const int tc = tid & 15;   // 0..15 -> cols tc*4..tc*4+3

  float acc[8][4] = {};

  for (int k0 = 0; k0 < K; k0 += BK) {
    // A tile: BM x BK = 2048 elems, 8 per thread
    #pragma unroll
    for (int i = 0; i < 8; i++) {
      int idx = tid + i * 256;
      int m  = idx >> 4;
      int kk = idx & 15;
      float v = 0.f;
      if (MODE == 1) {
        if (bm + m < M) {
          int tok = perm[start + bm + m];
          v = A[(size_t)tok * K + k0 + kk];
        }
      } else if (MODE == 2) {
        if (bm + m < M) v = A[(size_t)(bm + m) * K + k0 + kk];
      } else {
        v = A[(size_t)(bm + m) * K + k0 + kk];
      }
      As[kk][m] = v;
    }
    // B tile: BK x BN = 1024 elems, 4 per thread (coalesced rows of 64)
    #pragma unroll
    for (int i = 0; i < 4; i++) {
      int idx = tid + i * 256;
      int kk = idx >> 6;
      int n  = idx & 63;
      Bs[kk][n] = W[(size_t)(k0 + kk) * N + bn + n];
    }
    __syncthreads();
    #pragma unroll
    for (int kk = 0; kk < BK; kk++) {
      float4 a0 = *(const float4*)&As[kk][tr * 8];
      float4 a1 = *(const float4*)&As[kk][tr * 8 + 4];
      float4 b0 = *(const float4*)&Bs[kk][tc * 4];
      float a[8] = {a0.x, a0.y, a0.z, a0.w, a1.x, a1.y, a1.z, a1.w};
      float b[4] = {b0.x, b0.y, b0.z, b0.w};
      #pragma unroll
      for (int u = 0; u < 8; u++)
        #pragma unroll
        for (int v = 0; v < 4; v++)
          acc[u][v] = fmaf(a[u], b[v], acc[u][v]);
    }
    __syncthreads();
  }

  // epilogue
  if (MODE == 0) {
    #pragma unroll
    for (int u = 0; u < 8; u++) {
      int row = bm + tr * 8 + u;
      #pragma unroll
      for (int v = 0; v < 4; v++) {
        int col = bn + tc * 4 + v;
        C[(size_t)row * N + col] = acc[u][v] + bias[col];
      }
    }
  } else if (MODE == 1) {
    #pragma unroll
    for (int u = 0; u < 8; u++) {
      int r = bm + tr * 8 + u;
      if (r < M) {
        #pragma unroll
        for (int v = 0; v < 4; v++) {
          int col = bn + tc * 4 + v;
          C[(size_t)r * N + col] = gelu_tanh(acc[u][v] + bias[col]);
        }
      }
    }
  } else {
    #pragma unroll
    for (int u = 0; u < 8; u++) {
      int r = bm + tr * 8 + u;
      if (r < M) {
        int tok = perm[start + r];
        float g = gperm[start + r];
        #pragma unroll
        for (int v = 0; v < 4; v++) {
          int col = bn + tc * 4 + v;
          atomicAdd(&C[(size_t)tok * N + col], g * (acc[u][v] + bias[col]));
        }
      }
    }
  }
}

// ---------------- attention (flash-style, fp32) ----------------
// grid: (16 query tiles, B*H=48); block 256.
// 4 lanes per query row, each owns 16 of the 64 ctx dims.
__global__ __launch_bounds__(256) void attn_kernel(
    const float* __restrict__ qkv, float* __restrict__ ctx)
{
  const int qt = blockIdx.x;
  const int bh = blockIdx.y;
  const int b = bh / HEADS, h = bh % HEADS;
  const float* base = qkv + (size_t)b * 1024 * (3 * DIM);
  __shared__ float qs[64][68];
  __shared__ float ks[64][68];
  __shared__ float vs[64][68];
  const int tid = threadIdx.x;

  for (int i = tid; i < 64 * 64; i += 256) {
    int r = i >> 6, d = i & 63;
    qs[r][d] = base[(size_t)(qt * 64 + r) * (3 * DIM) + h * 64 + d] * 0.125f;
  }

  const int qi = tid >> 2;
  const int part = (tid & 3) * 16;
  float acc[16] = {};
  float m = -1e30f, l = 0.f;

  for (int kt = 0; kt < 16; kt++) {
    __syncthreads();  // also covers the qs load on kt==0
    for (int i = tid; i < 64 * 64; i += 256) {
      int r = i >> 6, d = i & 63;
      size_t rowoff = (size_t)(kt * 64 + r) * (3 * DIM) + h * 64 + d;
      ks[r][d] = base[rowoff + DIM];
      vs[r][d] = base[rowoff + 2 * DIM];
    }
    __syncthreads();
    #pragma unroll 4
    for (int j = 0; j < 64; j++) {
      float s = 0.f;
      #pragma unroll
      for (int d = 0; d < 16; d++) s = fmaf(qs[qi][part + d], ks[j][part + d], s);
      s += __shfl_xor(s, 1);
      s += __shfl_xor(s, 2);
      float mn = fmaxf(m, s);
      float sc = __expf(m - mn);
      float p  = __expf(s - mn);
      l = l * sc + p;
      m = mn;
      #pragma unroll
      for (int d = 0; d < 16; d++) acc[d] = fmaf(p, vs[j][part + d], acc[d] * sc);
    }
  }
  float inv = 1.f / l;
  size_t orow = ((size_t)b * 1024 + qt * 64 + qi) * DIM + h * 64 + part;
  #pragma unroll
  for (int d = 0; d < 16; d++) ctx[orow + d] = acc[d] * inv;
}

// ---------------- router: logits, softmax, top-2, histogram ----------------
__global__ __launch_bounds__(256) void router_kernel(
    const float* __restrict__ y, const float* __restrict__ wr,
    float* __restrict__ probs, int* __restrict__ topi,
    float* __restrict__ topg, int* __restrict__ counts)
{
  __shared__ float w[DIM * NEXP];
  const int tid = threadIdx.x;
  for (int i = tid; i < DIM * NEXP; i += 256) w[i] = wr[i];
  __syncthreads();

  const int t = blockIdx.x * 256 + tid;  // 16 blocks * 256 = 4096 exactly
  const float* yp = y + (size_t)t * DIM;
  float logit[8] = {};
  for (int d = 0; d < DIM; d++) {
    float xv = yp[d];
    #pragma unroll
    for (int e = 0; e < 8; e++) logit[e] = fmaf(xv, w[d * 8 + e], logit[e]);
  }
  float mx = logit[0];
  #pragma unroll
  for (int e = 1; e < 8; e++) mx = fmaxf(mx, logit[e]);
  float p[8], sum = 0.f;
  #pragma unroll
  for (int e = 0; e < 8; e++) { p[e] = __expf(logit[e] - mx); sum += p[e]; }
  float inv = 1.f / sum;
  #pragma unroll
  for (int e = 0; e < 8; e++) { p[e] *= inv; probs[(size_t)t * 8 + e] = p[e]; }

  int i0 = 0;
  #pragma unroll
  for (int e = 1; e < 8; e++) if (p[e] > p[i0]) i0 = e;
  int i1 = (i0 == 0) ? 1 : 0;
  #pragma unroll
  for (int e = 0; e < 8; e++) if (e != i0 && p[e] > p[i1]) i1 = e;
  float g = p[i0] + p[i1];
  topi[2 * t] = i0;  topi[2 * t + 1] = i1;
  topg[2 * t] = p[i0] / g;  topg[2 * t + 1] = p[i1] / g;
  atomicAdd(&counts[i0], 1);
  atomicAdd(&counts[i1], 1);
}

__global__ void init_meta(int* counts) {
  if (threadIdx.x < 8) counts[threadIdx.x] = 0;
}

__global__ void scan_kernel(const int* __restrict__ counts,
                            int* __restrict__ offsets, int* __restrict__ cursors) {
  if (threadIdx.x == 0) {
    int s = 0;
    for (int e = 0; e < 8; e++) { offsets[e] = s; cursors[e] = s; s += counts[e]; }
    offsets[8] = s;
  }
}

__global__ __launch_bounds__(256) void scatter_kernel(
    const int* __restrict__ topi, const float* __restrict__ topg,
    int* __restrict__ cursors, int* __restrict__ perm, float* __restrict__ gperm)
{
  const int t = blockIdx.x * 256 + threadIdx.x;  // exactly 4096
  #pragma unroll
  for (int s = 0; s < 2; s++) {
    int e = topi[2 * t + s];
    int pos = atomicAdd(&cursors[e], 1);
    perm[pos] = t;
    gperm[pos] = topg[2 * t + s];
  }
}

// ---------------- launch ----------------
extern "C" void kernel_launch(void* const* d_in, const int* in_sizes, int n_in,
                              void* d_out, int out_size, void* d_ws, size_t ws_size,
                              hipStream_t stream) {
  const float* x        = (const float*)d_in[0];
  const float* w_qkv    = (const float*)d_in[1];
  const float* b_qkv    = (const float*)d_in[2];
  const float* w_o      = (const float*)d_in[3];
  const float* b_o      = (const float*)d_in[4];
  const float* w_router = (const float*)d_in[5];
  const float* w1       = (const float*)d_in[6];
  const float* b1       = (const float*)d_in[7];
  const float* w2       = (const float*)d_in[8];
  const float* b2       = (const float*)d_in[9];

  float* out   = (float*)d_out;                 // [4096,768]
  float* probs = out + (size_t)T_TOK * DIM;     // [4096,8]

  char* ws = (char*)d_ws;
  // region A (union): qkv [4096*2304] = 37.75MB, later hbuf [4096*3072] = 50.33MB
  float* qkv  = (float*)ws;
  float* hbuf = (float*)ws;
  float* ctx  = (float*)(ws + 50331648);   // 12.58MB
  float* y    = (float*)(ws + 62914560);   // 12.58MB
  char*  meta = ws + 75497472;
  int*   counts  = (int*)meta;
  int*   cursors = counts + 8;
  int*   offsets = cursors + 8;            // 16 slots
  int*   topi    = offsets + 16;           // 8192
  float* topg    = (float*)(topi + 8192);
  int*   perm    = (int*)(topg + 8192);
  float* gperm   = (float*)(perm + 8192);

  hipMemsetAsync(d_out, 0, (size_t)out_size * sizeof(float), stream);
  init_meta<<<1, 64, 0, stream>>>(counts);

  // QKV: [4096,768] @ [768,2304]
  gemm_k<0><<<dim3((3 * DIM) / BN, T_TOK / BM), 256, 0, stream>>>(
      x, w_qkv, b_qkv, qkv, T_TOK, 3 * DIM, DIM, nullptr, nullptr, nullptr, 0);

  // attention
  attn_kernel<<<dim3(16, 48), 256, 0, stream>>>(qkv, ctx);

  // output proj: [4096,768] @ [768,768]
  gemm_k<0><<<dim3(DIM / BN, T_TOK / BM), 256, 0, stream>>>(
      ctx, w_o, b_o, y, T_TOK, DIM, DIM, nullptr, nullptr, nullptr, 0);

  // router + top2 + histogram
  router_kernel<<<16, 256, 0, stream>>>(y, w_router, probs, topi, topg, counts);
  scan_kernel<<<1, 64, 0, stream>>>(counts, offsets, cursors);
  scatter_kernel<<<16, 256, 0, stream>>>(topi, topg, cursors, perm, gperm);

  // MoE: 8 experts sequentially, hbuf reused (worst-case 4096 rows)
  for (int e = 0; e < NEXP; e++) {
    gemm_k<1><<<dim3(FDIM / BN, T_TOK / BM), 256, 0, stream>>>(
        y, w1 + (size_t)e * DIM * FDIM, b1 + (size_t)e * FDIM, hbuf,
        0, FDIM, DIM, offsets, perm, gperm, e);
    gemm_k<2><<<dim3(DIM / BN, T_TOK / BM), 256, 0, stream>>>(
        hbuf, w2 + (size_t)e * FDIM * DIM, b2 + (size_t)e * DIM, out,
        0, DIM, FDIM, offsets, perm, gperm, e);
  }
}

// Round 2
// 1449.797 us; speedup vs baseline: 4.2673x; 4.2673x over previous
//
#include <hip/hip_runtime.h>
#include <hip/hip_bf16.h>
#include <cstdint>
#include <cmath>

#define T_TOK 4096
#define DIM   768
#define HEADS 12
#define HD    64
#define NEXP  8
#define FDIM  3072

typedef __attribute__((ext_vector_type(8))) short short8v;
typedef __attribute__((ext_vector_type(4))) float float4v;

__device__ __forceinline__ float gelu_tanh(float x) {
  // matches jax.nn.gelu(approximate=True)
  float u = 0.7978845608028654f * (x + 0.044715f * x * x * x);
  return 0.5f * x * (1.0f + tanhf(u));
}

__device__ __forceinline__ short f2bf(float x) {
  __hip_bfloat16 h = __float2bfloat16(x);
  return *reinterpret_cast<short*>(&h);
}

// ---------------- fp32 tiled GEMM (attention path only: QKV, o-proj) --------
#define BM 128
#define BN 64
#define BK 16

__global__ __launch_bounds__(256) void gemm_f32(
    const float* __restrict__ A, const float* __restrict__ W,
    const float* __restrict__ bias, float* __restrict__ C,
    int M, int N, int K)
{
  __shared__ float As[BK][BM + 4];
  __shared__ float Bs[BK][BN + 4];
  const int bm = blockIdx.y * BM;
  const int bn = blockIdx.x * BN;
  const int tid = threadIdx.x;
  const int tr = tid >> 4;
  const int tc = tid & 15;

  float acc[8][4] = {};

  for (int k0 = 0; k0 < K; k0 += BK) {
    #pragma unroll
    for (int i = 0; i < 8; i++) {
      int idx = tid + i * 256;
      int m  = idx >> 4;
      int kk = idx & 15;
      As[kk][m] = A[(size_t)(bm + m) * K + k0 + kk];
    }
    #pragma unroll
    for (int i = 0; i < 4; i++) {
      int idx = tid + i * 256;
      int kk = idx >> 6;
      int n  = idx & 63;
      Bs[kk][n] = W[(size_t)(k0 + kk) * N + bn + n];
    }
    __syncthreads();
    #pragma unroll
    for (int kk = 0; kk < BK; kk++) {
      float4 a0 = *(const float4*)&As[kk][tr * 8];
      float4 a1 = *(const float4*)&As[kk][tr * 8 + 4];
      float4 b0 = *(const float4*)&Bs[kk][tc * 4];
      float a[8] = {a0.x, a0.y, a0.z, a0.w, a1.x, a1.y, a1.z, a1.w};
      float b[4] = {b0.x, b0.y, b0.z, b0.w};
      #pragma unroll
      for (int u = 0; u < 8; u++)
        #pragma unroll
        for (int v = 0; v < 4; v++)
          acc[u][v] = fmaf(a[u], b[v], acc[u][v]);
    }
    __syncthreads();
  }

  #pragma unroll
  for (int u = 0; u < 8; u++) {
    int row = bm + tr * 8 + u;
    #pragma unroll
    for (int v = 0; v < 4; v++) {
      int col = bn + tc * 4 + v;
      C[(size_t)row * N + col] = acc[u][v] + bias[col];
    }
  }
}

// ---------------- transpose + fp32->bf16 convert: W[K][N] -> WT[N][K] -------
__global__ __launch_bounds__(256) void transpose_bf16(
    const float* __restrict__ W, short* __restrict__ WT, int K, int N)
{
  __shared__ float t[32][33];
  const size_t mat = (size_t)K * N;
  const float* Wp = W + blockIdx.z * mat;
  short* WTp = WT + blockIdx.z * mat;
  int n0 = blockIdx.x * 32, k0 = blockIdx.y * 32;
  int tx = threadIdx.x, ty = threadIdx.y;  // 32 x 8
  #pragma unroll
  for (int i = 0; i < 4; i++)
    t[ty + i * 8][tx] = Wp[(size_t)(k0 + ty + i * 8) * N + n0 + tx];
  __syncthreads();
  #pragma unroll
  for (int i = 0; i < 4; i++)
    WTp[(size_t)(n0 + ty + i * 8) * K + k0 + tx] = f2bf(t[tx][ty + i * 8]);
}

// ---------------- bf16 MFMA GEMM for MoE -----------------------------------
// 128x128 tile, BK=32, 256 threads = 4 waves (2x2), 16x16x32 MFMA, 4x4 frags.
// MODE 1: hbuf[start+r] = gelu(gather(y,perm)[r] @ W1T^T + b1)   (A fp32, gathered)
// MODE 2: atomicAdd(out[perm[start+r]], g * (hbuf[start+r] @ W2T^T + b2))  (A bf16)
template<int MODE>
__global__ __launch_bounds__(256) void moe_mfma(
    const void* __restrict__ Araw, const short* __restrict__ WT,
    const float* __restrict__ bias, void* __restrict__ Craw,
    int N, int K,
    const int* __restrict__ offsets, const int* __restrict__ perm,
    const float* __restrict__ gperm)
{
  const int e = blockIdx.z;
  const int start = offsets[e];
  const int M = offsets[e + 1] - start;
  const int bm = blockIdx.y * 128;
  if (bm >= M) return;
  const int bn = blockIdx.x * 128;

  __shared__ short As[4][128][8];
  __shared__ short Bs[4][128][8];
  __shared__ int   perm_s[128];
  __shared__ float g_s[128];

  const int tid  = threadIdx.x;
  const int lane = tid & 63;
  const int wave = tid >> 6;
  const int wm = wave >> 1, wn = wave & 1;
  const int lr = lane & 15;
  const int kb = lane >> 4;

  const short* WTe = WT + (size_t)e * ((size_t)N * K);
  const float* be  = bias + (size_t)e * N;

  if (tid < 128) {
    int rr = bm + tid;
    perm_s[tid] = (rr < M) ? perm[start + rr] : 0;
    g_s[tid]    = (rr < M) ? gperm[start + rr] : 0.f;
  }
  __syncthreads();

  // precompute staging row pointers (rows fixed across k-steps)
  const float* aptr32[4];
  const short* aptr16[2];
  const short* bptr[2];
  int ac = 0, aq = 0, bq = tid & 3;
  if (MODE == 1) {
    const float* A = (const float*)Araw;
    ac = tid & 7;
    #pragma unroll
    for (int i = 0; i < 4; i++) {
      int m = (tid >> 3) + i * 32;
      aptr32[i] = A + (size_t)perm_s[m] * K;
    }
  } else {
    const short* A = (const short*)Araw;
    aq = tid & 3;
    #pragma unroll
    for (int i = 0; i < 2; i++) {
      int m = (tid >> 2) + i * 64;
      int rr = bm + m; if (rr >= M) rr = 0;
      aptr16[i] = A + (size_t)(start + rr) * K;
    }
  }
  #pragma unroll
  for (int i = 0; i < 2; i++) {
    int n = (tid >> 2) + i * 64;
    bptr[i] = WTe + (size_t)(bn + n) * K;
  }

  float4v acc[4][4] = {};

  for (int k0 = 0; k0 < K; k0 += 32) {
    // issue global loads early
    float4 av32[4];
    int4   av16[2];
    int4   bv[2];
    if (MODE == 1) {
      #pragma unroll
      for (int i = 0; i < 4; i++) av32[i] = *(const float4*)(aptr32[i] + k0 + ac * 4);
    } else {
      #pragma unroll
      for (int i = 0; i < 2; i++) av16[i] = *(const int4*)(aptr16[i] + k0 + aq * 8);
    }
    #pragma unroll
    for (int i = 0; i < 2; i++) bv[i] = *(const int4*)(bptr[i] + k0 + bq * 8);

    __syncthreads();   // previous iteration's LDS reads complete

    if (MODE == 1) {
      #pragma unroll
      for (int i = 0; i < 4; i++) {
        int m = (tid >> 3) + i * 32;
        short4 p = make_short4(f2bf(av32[i].x), f2bf(av32[i].y),
                               f2bf(av32[i].z), f2bf(av32[i].w));
        *(short4*)&As[ac >> 1][m][(ac & 1) * 4] = p;
      }
    } else {
      #pragma unroll
      for (int i = 0; i < 2; i++) {
        int m = (tid >> 2) + i * 64;
        *(int4*)&As[aq][m][0] = av16[i];
      }
    }
    #pragma unroll
    for (int i = 0; i < 2; i++) {
      int n = (tid >> 2) + i * 64;
      *(int4*)&Bs[bq][n][0] = bv[i];
    }

    __syncthreads();   // tiles visible

    short8v af[4], bfv[4];
    #pragma unroll
    for (int mi = 0; mi < 4; mi++)
      af[mi] = *(const short8v*)&As[kb][wm * 64 + mi * 16 + lr][0];
    #pragma unroll
    for (int ni = 0; ni < 4; ni++)
      bfv[ni] = *(const short8v*)&Bs[kb][wn * 64 + ni * 16 + lr][0];
    #pragma unroll
    for (int mi = 0; mi < 4; mi++)
      #pragma unroll
      for (int ni = 0; ni < 4; ni++)
        acc[mi][ni] = __builtin_amdgcn_mfma_f32_16x16x32_bf16(
            af[mi], bfv[ni], acc[mi][ni], 0, 0, 0);
  }

  // epilogue; D mapping: col = lane&15, row = (lane>>4)*4 + reg
  #pragma unroll
  for (int ni = 0; ni < 4; ni++) {
    int col = bn + wn * 64 + ni * 16 + lr;
    float b = be[col];
    #pragma unroll
    for (int mi = 0; mi < 4; mi++) {
      int lrow0 = wm * 64 + mi * 16 + kb * 4;
      #pragma unroll
      for (int r = 0; r < 4; r++) {
        int lrow = lrow0 + r;
        int rr = bm + lrow;
        if (rr < M) {
          if (MODE == 1) {
            short* C = (short*)Craw;
            C[(size_t)(start + rr) * N + col] = f2bf(gelu_tanh(acc[mi][ni][r] + b));
          } else {
            float* C = (float*)Craw;
            int tok = perm_s[lrow];
            atomicAdd(&C[(size_t)tok * DIM + col], g_s[lrow] * (acc[mi][ni][r] + b));
          }
        }
      }
    }
  }
}

// ---------------- attention (flash-style, fp32) ----------------
__global__ __launch_bounds__(256) void attn_kernel(
    const float* __restrict__ qkv, float* __restrict__ ctx)
{
  const int qt = blockIdx.x;
  const int bh = blockIdx.y;
  const int b = bh / HEADS, h = bh % HEADS;
  const float* base = qkv + (size_t)b * 1024 * (3 * DIM);
  __shared__ float qs[64][68];
  __shared__ float ks[64][68];
  __shared__ float vs[64][68];
  const int tid = threadIdx.x;

  for (int i = tid; i < 64 * 64; i += 256) {
    int r = i >> 6, d = i & 63;
    qs[r][d] = base[(size_t)(qt * 64 + r) * (3 * DIM) + h * 64 + d] * 0.125f;
  }

  const int qi = tid >> 2;
  const int part = (tid & 3) * 16;
  float acc[16] = {};
  float m = -1e30f, l = 0.f;

  for (int kt = 0; kt < 16; kt++) {
    __syncthreads();
    for (int i = tid; i < 64 * 64; i += 256) {
      int r = i >> 6, d = i & 63;
      size_t rowoff = (size_t)(kt * 64 + r) * (3 * DIM) + h * 64 + d;
      ks[r][d] = base[rowoff + DIM];
      vs[r][d] = base[rowoff + 2 * DIM];
    }
    __syncthreads();
    #pragma unroll 4
    for (int j = 0; j < 64; j++) {
      float s = 0.f;
      #pragma unroll
      for (int d = 0; d < 16; d++) s = fmaf(qs[qi][part + d], ks[j][part + d], s);
      s += __shfl_xor(s, 1);
      s += __shfl_xor(s, 2);
      float mn = fmaxf(m, s);
      float sc = __expf(m - mn);
      float p  = __expf(s - mn);
      l = l * sc + p;
      m = mn;
      #pragma unroll
      for (int d = 0; d < 16; d++) acc[d] = fmaf(p, vs[j][part + d], acc[d] * sc);
    }
  }
  float inv = 1.f / l;
  size_t orow = ((size_t)b * 1024 + qt * 64 + qi) * DIM + h * 64 + part;
  #pragma unroll
  for (int d = 0; d < 16; d++) ctx[orow + d] = acc[d] * inv;
}

// ---------------- router ----------------
__global__ __launch_bounds__(256) void router_kernel(
    const float* __restrict__ y, const float* __restrict__ wr,
    float* __restrict__ probs, int* __restrict__ topi,
    float* __restrict__ topg, int* __restrict__ counts)
{
  __shared__ float w[DIM * NEXP];
  const int tid = threadIdx.x;
  for (int i = tid; i < DIM * NEXP; i += 256) w[i] = wr[i];
  __syncthreads();

  const int t = blockIdx.x * 256 + tid;
  const float* yp = y + (size_t)t * DIM;
  float logit[8] = {};
  for (int d = 0; d < DIM; d++) {
    float xv = yp[d];
    #pragma unroll
    for (int e = 0; e < 8; e++) logit[e] = fmaf(xv, w[d * 8 + e], logit[e]);
  }
  float mx = logit[0];
  #pragma unroll
  for (int e = 1; e < 8; e++) mx = fmaxf(mx, logit[e]);
  float p[8], sum = 0.f;
  #pragma unroll
  for (int e = 0; e < 8; e++) { p[e] = __expf(logit[e] - mx); sum += p[e]; }
  float inv = 1.f / sum;
  #pragma unroll
  for (int e = 0; e < 8; e++) { p[e] *= inv; probs[(size_t)t * 8 + e] = p[e]; }

  int i0 = 0;
  #pragma unroll
  for (int e = 1; e < 8; e++) if (p[e] > p[i0]) i0 = e;
  int i1 = (i0 == 0) ? 1 : 0;
  #pragma unroll
  for (int e = 0; e < 8; e++) if (e != i0 && p[e] > p[i1]) i1 = e;
  float g = p[i0] + p[i1];
  topi[2 * t] = i0;  topi[2 * t + 1] = i1;
  topg[2 * t] = p[i0] / g;  topg[2 * t + 1] = p[i1] / g;
  atomicAdd(&counts[i0], 1);
  atomicAdd(&counts[i1], 1);
}

__global__ void init_meta(int* counts) {
  if (threadIdx.x < 8) counts[threadIdx.x] = 0;
}

__global__ void scan_kernel(const int* __restrict__ counts,
                            int* __restrict__ offsets, int* __restrict__ cursors) {
  if (threadIdx.x == 0) {
    int s = 0;
    for (int e = 0; e < 8; e++) { offsets[e] = s; cursors[e] = s; s += counts[e]; }
    offsets[8] = s;
  }
}

__global__ __launch_bounds__(256) void scatter_kernel(
    const int* __restrict__ topi, const float* __restrict__ topg,
    int* __restrict__ cursors, int* __restrict__ perm, float* __restrict__ gperm)
{
  const int t = blockIdx.x * 256 + threadIdx.x;
  #pragma unroll
  for (int s = 0; s < 2; s++) {
    int e = topi[2 * t + s];
    int pos = atomicAdd(&cursors[e], 1);
    perm[pos] = t;
    gperm[pos] = topg[2 * t + s];
  }
}

// ---------------- launch ----------------
extern "C" void kernel_launch(void* const* d_in, const int* in_sizes, int n_in,
                              void* d_out, int out_size, void* d_ws, size_t ws_size,
                              hipStream_t stream) {
  const float* x        = (const float*)d_in[0];
  const float* w_qkv    = (const float*)d_in[1];
  const float* b_qkv    = (const float*)d_in[2];
  const float* w_o      = (const float*)d_in[3];
  const float* b_o      = (const float*)d_in[4];
  const float* w_router = (const float*)d_in[5];
  const float* w1       = (const float*)d_in[6];
  const float* b1       = (const float*)d_in[7];
  const float* w2       = (const float*)d_in[8];
  const float* b2       = (const float*)d_in[9];

  float* out   = (float*)d_out;
  float* probs = out + (size_t)T_TOK * DIM;

  char* ws = (char*)d_ws;
  // region B (union): qkv fp32 [4096*2304]=37.75MB, later hbuf bf16 [8192*3072]=50.33MB
  float* qkv  = (float*)ws;
  short* hbuf = (short*)ws;
  short* wT   = (short*)(ws + 50331648);     // 37.75MB (w1t, then w2t)
  float* ctx  = (float*)(ws + 88080384);     // 12.58MB
  float* y    = (float*)(ws + 100663296);    // 12.58MB
  char*  meta = ws + 113246208;
  int*   counts  = (int*)meta;
  int*   cursors = counts + 8;
  int*   offsets = cursors + 8;
  int*   topi    = offsets + 16;
  float* topg    = (float*)(topi + 8192);
  int*   perm    = (int*)(topg + 8192);
  float* gperm   = (float*)(perm + 8192);

  hipMemsetAsync(d_out, 0, (size_t)out_size * sizeof(float), stream);
  init_meta<<<1, 64, 0, stream>>>(counts);

  // QKV (fp32): [4096,768] @ [768,2304]
  gemm_f32<<<dim3((3 * DIM) / BN, T_TOK / BM), 256, 0, stream>>>(
      x, w_qkv, b_qkv, qkv, T_TOK, 3 * DIM, DIM);

  attn_kernel<<<dim3(16, 48), 256, 0, stream>>>(qkv, ctx);

  // output proj (fp32): [4096,768] @ [768,768]
  gemm_f32<<<dim3(DIM / BN, T_TOK / BM), 256, 0, stream>>>(
      ctx, w_o, b_o, y, T_TOK, DIM, DIM);

  router_kernel<<<16, 256, 0, stream>>>(y, w_router, probs, topi, topg, counts);
  scan_kernel<<<1, 64, 0, stream>>>(counts, offsets, cursors);
  scatter_kernel<<<16, 256, 0, stream>>>(topi, topg, cursors, perm, gperm);

  // w1 [8][768][3072] -> w1t bf16 [8][3072][768]
  transpose_bf16<<<dim3(FDIM / 32, DIM / 32, NEXP), dim3(32, 8), 0, stream>>>(
      w1, wT, DIM, FDIM);
  // up-proj: all experts in one launch
  moe_mfma<1><<<dim3(FDIM / 128, T_TOK / 128, NEXP), 256, 0, stream>>>(
      y, wT, b1, hbuf, FDIM, DIM, offsets, perm, gperm);
  // w2 [8][3072][768] -> w2t bf16 [8][768][3072]
  transpose_bf16<<<dim3(DIM / 32, FDIM / 32, NEXP), dim3(32, 8), 0, stream>>>(
      w2, wT, FDIM, DIM);
  // down-proj + weighted scatter-add
  moe_mfma<2><<<dim3(DIM / 128, T_TOK / 128, NEXP), 256, 0, stream>>>(
      hbuf, wT, b2, out, DIM, FDIM, offsets, perm, gperm);
}

// Round 3
// 1269.428 us; speedup vs baseline: 4.8736x; 1.1421x over previous
//
#include <hip/hip_runtime.h>
#include <hip/hip_bf16.h>
#include <cstdint>
#include <cmath>

#define T_TOK 4096
#define DIM   768
#define HEADS 12
#define HD    64
#define NEXP  8
#define FDIM  3072

typedef __attribute__((ext_vector_type(8))) short short8v;
typedef __attribute__((ext_vector_type(4))) float float4v;

__device__ __forceinline__ float gelu_tanh(float x) {
  // matches jax.nn.gelu(approximate=True)
  float u = 0.7978845608028654f * (x + 0.044715f * x * x * x);
  return 0.5f * x * (1.0f + tanhf(u));
}

__device__ __forceinline__ short f2bf(float x) {
  __hip_bfloat16 h = __float2bfloat16(x);
  return *reinterpret_cast<short*>(&h);
}

// ---------------- fp32 tiled GEMM (attention path only: QKV, o-proj) --------
// 16x16 thread grid, micro-tile (TBM/16)x(TBN/16), BK=16.
template<int TBM, int TBN>
__global__ __launch_bounds__(256) void gemm_f32(
    const float* __restrict__ A, const float* __restrict__ W,
    const float* __restrict__ bias, float* __restrict__ C,
    int M, int N, int K)
{
  constexpr int MM = TBM / 16;
  constexpr int MN = TBN / 16;
  constexpr int ALOAD = TBM * 16 / 256;
  constexpr int BLOAD = TBN * 16 / 256;
  __shared__ float As[16][TBM + 4];
  __shared__ float Bs[16][TBN + 4];
  const int bm = blockIdx.y * TBM;
  const int bn = blockIdx.x * TBN;
  const int tid = threadIdx.x;
  const int tr = tid >> 4;
  const int tc = tid & 15;

  float acc[MM][MN] = {};

  for (int k0 = 0; k0 < K; k0 += 16) {
    #pragma unroll
    for (int i = 0; i < ALOAD; i++) {
      int idx = tid + i * 256;
      int m  = idx >> 4;
      int kk = idx & 15;
      As[kk][m] = A[(size_t)(bm + m) * K + k0 + kk];
    }
    #pragma unroll
    for (int i = 0; i < BLOAD; i++) {
      int idx = tid + i * 256;
      int kk = idx / TBN;
      int n  = idx % TBN;
      Bs[kk][n] = W[(size_t)(k0 + kk) * N + bn + n];
    }
    __syncthreads();
    #pragma unroll
    for (int kk = 0; kk < 16; kk++) {
      float a[MM], b[MN];
      #pragma unroll
      for (int u4 = 0; u4 < MM / 4; u4++) {
        float4 t = *(const float4*)&As[kk][tr * MM + u4 * 4];
        a[u4*4+0]=t.x; a[u4*4+1]=t.y; a[u4*4+2]=t.z; a[u4*4+3]=t.w;
      }
      #pragma unroll
      for (int v4 = 0; v4 < MN / 4; v4++) {
        float4 t = *(const float4*)&Bs[kk][tc * MN + v4 * 4];
        b[v4*4+0]=t.x; b[v4*4+1]=t.y; b[v4*4+2]=t.z; b[v4*4+3]=t.w;
      }
      #pragma unroll
      for (int u = 0; u < MM; u++)
        #pragma unroll
        for (int v = 0; v < MN; v++)
          acc[u][v] = fmaf(a[u], b[v], acc[u][v]);
    }
    __syncthreads();
  }

  #pragma unroll
  for (int u = 0; u < MM; u++) {
    int row = bm + tr * MM + u;
    #pragma unroll
    for (int v4 = 0; v4 < MN / 4; v4++) {
      int col = bn + tc * MN + v4 * 4;
      float4 o;
      o.x = acc[u][v4*4+0] + bias[col+0];
      o.y = acc[u][v4*4+1] + bias[col+1];
      o.z = acc[u][v4*4+2] + bias[col+2];
      o.w = acc[u][v4*4+3] + bias[col+3];
      *(float4*)&C[(size_t)row * N + col] = o;
    }
  }
}

// ---------------- transpose + fp32->bf16 convert: W[K][N] -> WT[N][K] -------
__global__ __launch_bounds__(256) void transpose_bf16(
    const float* __restrict__ W, short* __restrict__ WT, int K, int N)
{
  __shared__ float t[32][33];
  const size_t mat = (size_t)K * N;
  const float* Wp = W + blockIdx.z * mat;
  short* WTp = WT + blockIdx.z * mat;
  int n0 = blockIdx.x * 32, k0 = blockIdx.y * 32;
  int tx = threadIdx.x, ty = threadIdx.y;  // 32 x 8
  #pragma unroll
  for (int i = 0; i < 4; i++)
    t[ty + i * 8][tx] = Wp[(size_t)(k0 + ty + i * 8) * N + n0 + tx];
  __syncthreads();
  #pragma unroll
  for (int i = 0; i < 4; i++)
    WTp[(size_t)(n0 + ty + i * 8) * K + k0 + tx] = f2bf(t[tx][ty + i * 8]);
}

// ---------------- bf16 MFMA GEMM for MoE -----------------------------------
template<int MODE>
__global__ __launch_bounds__(256) void moe_mfma(
    const void* __restrict__ Araw, const short* __restrict__ WT,
    const float* __restrict__ bias, void* __restrict__ Craw,
    int N, int K,
    const int* __restrict__ offsets, const int* __restrict__ perm,
    const float* __restrict__ gperm)
{
  const int e = blockIdx.z;
  const int start = offsets[e];
  const int M = offsets[e + 1] - start;
  const int bm = blockIdx.y * 128;
  if (bm >= M) return;
  const int bn = blockIdx.x * 128;

  __shared__ short As[4][128][8];
  __shared__ short Bs[4][128][8];
  __shared__ int   perm_s[128];
  __shared__ float g_s[128];

  const int tid  = threadIdx.x;
  const int lane = tid & 63;
  const int wave = tid >> 6;
  const int wm = wave >> 1, wn = wave & 1;
  const int lr = lane & 15;
  const int kb = lane >> 4;

  const short* WTe = WT + (size_t)e * ((size_t)N * K);
  const float* be  = bias + (size_t)e * N;

  if (tid < 128) {
    int rr = bm + tid;
    perm_s[tid] = (rr < M) ? perm[start + rr] : 0;
    g_s[tid]    = (rr < M) ? gperm[start + rr] : 0.f;
  }
  __syncthreads();

  const float* aptr32[4];
  const short* aptr16[2];
  const short* bptr[2];
  int ac = 0, aq = 0, bq = tid & 3;
  if (MODE == 1) {
    const float* A = (const float*)Araw;
    ac = tid & 7;
    #pragma unroll
    for (int i = 0; i < 4; i++) {
      int m = (tid >> 3) + i * 32;
      aptr32[i] = A + (size_t)perm_s[m] * K;
    }
  } else {
    const short* A = (const short*)Araw;
    aq = tid & 3;
    #pragma unroll
    for (int i = 0; i < 2; i++) {
      int m = (tid >> 2) + i * 64;
      int rr = bm + m; if (rr >= M) rr = 0;
      aptr16[i] = A + (size_t)(start + rr) * K;
    }
  }
  #pragma unroll
  for (int i = 0; i < 2; i++) {
    int n = (tid >> 2) + i * 64;
    bptr[i] = WTe + (size_t)(bn + n) * K;
  }

  float4v acc[4][4] = {};

  for (int k0 = 0; k0 < K; k0 += 32) {
    float4 av32[4];
    int4   av16[2];
    int4   bv[2];
    if (MODE == 1) {
      #pragma unroll
      for (int i = 0; i < 4; i++) av32[i] = *(const float4*)(aptr32[i] + k0 + ac * 4);
    } else {
      #pragma unroll
      for (int i = 0; i < 2; i++) av16[i] = *(const int4*)(aptr16[i] + k0 + aq * 8);
    }
    #pragma unroll
    for (int i = 0; i < 2; i++) bv[i] = *(const int4*)(bptr[i] + k0 + bq * 8);

    __syncthreads();

    if (MODE == 1) {
      #pragma unroll
      for (int i = 0; i < 4; i++) {
        int m = (tid >> 3) + i * 32;
        short4 p = make_short4(f2bf(av32[i].x), f2bf(av32[i].y),
                               f2bf(av32[i].z), f2bf(av32[i].w));
        *(short4*)&As[ac >> 1][m][(ac & 1) * 4] = p;
      }
    } else {
      #pragma unroll
      for (int i = 0; i < 2; i++) {
        int m = (tid >> 2) + i * 64;
        *(int4*)&As[aq][m][0] = av16[i];
      }
    }
    #pragma unroll
    for (int i = 0; i < 2; i++) {
      int n = (tid >> 2) + i * 64;
      *(int4*)&Bs[bq][n][0] = bv[i];
    }

    __syncthreads();

    short8v af[4], bfv[4];
    #pragma unroll
    for (int mi = 0; mi < 4; mi++)
      af[mi] = *(const short8v*)&As[kb][wm * 64 + mi * 16 + lr][0];
    #pragma unroll
    for (int ni = 0; ni < 4; ni++)
      bfv[ni] = *(const short8v*)&Bs[kb][wn * 64 + ni * 16 + lr][0];
    #pragma unroll
    for (int mi = 0; mi < 4; mi++)
      #pragma unroll
      for (int ni = 0; ni < 4; ni++)
        acc[mi][ni] = __builtin_amdgcn_mfma_f32_16x16x32_bf16(
            af[mi], bfv[ni], acc[mi][ni], 0, 0, 0);
  }

  #pragma unroll
  for (int ni = 0; ni < 4; ni++) {
    int col = bn + wn * 64 + ni * 16 + lr;
    float b = be[col];
    #pragma unroll
    for (int mi = 0; mi < 4; mi++) {
      int lrow0 = wm * 64 + mi * 16 + kb * 4;
      #pragma unroll
      for (int r = 0; r < 4; r++) {
        int lrow = lrow0 + r;
        int rr = bm + lrow;
        if (rr < M) {
          if (MODE == 1) {
            short* C = (short*)Craw;
            C[(size_t)(start + rr) * N + col] = f2bf(gelu_tanh(acc[mi][ni][r] + b));
          } else {
            float* C = (float*)Craw;
            int tok = perm_s[lrow];
            atomicAdd(&C[(size_t)tok * DIM + col], g_s[lrow] * (acc[mi][ni][r] + b));
          }
        }
      }
    }
  }
}

// ---------------- attention (fp32, no-max softmax, key-split waves) --------
// grid (16, 48), block 256 = 4 waves: wave = (khalf, qhalf).
// Each lane: 2 queries x 16 dims, q in registers; k/v tiles in LDS.
__global__ __launch_bounds__(256) void attn_kernel(
    const float* __restrict__ qkv, float* __restrict__ ctx)
{
  const int qt = blockIdx.x;
  const int bh = blockIdx.y;
  const int b = bh / HEADS, h = bh % HEADS;
  const float* base = qkv + (size_t)b * 1024 * (3 * DIM) + h * 64;

  __shared__ float ks[64][64];
  __shared__ float vs[64][64];

  const int tid   = threadIdx.x;
  const int wv    = tid >> 6;
  const int qhalf = wv & 1;
  const int khalf = wv >> 1;
  const int lane  = tid & 63;
  const int grp   = lane >> 2;
  const int sub   = lane & 3;
  const int q0    = qhalf * 32 + grp * 2;   // queries q0, q0+1
  const int dpart = sub * 16;

  // scale folds 1/sqrt(hd) and log2(e) so p = exp2(s)
  const float qscale = 0.125f * 1.44269504088896f;
  float qA[16], qB[16], accA[16] = {}, accB[16] = {};
  float lA = 0.f, lB = 0.f;

  {
    const float* qpA = base + (size_t)(qt * 64 + q0) * (3 * DIM) + dpart;
    const float* qpB = qpA + 3 * DIM;
    #pragma unroll
    for (int d4 = 0; d4 < 4; d4++) {
      float4 ta = *(const float4*)(qpA + d4 * 4);
      float4 tb = *(const float4*)(qpB + d4 * 4);
      qA[d4*4+0]=ta.x*qscale; qA[d4*4+1]=ta.y*qscale; qA[d4*4+2]=ta.z*qscale; qA[d4*4+3]=ta.w*qscale;
      qB[d4*4+0]=tb.x*qscale; qB[d4*4+1]=tb.y*qscale; qB[d4*4+2]=tb.z*qscale; qB[d4*4+3]=tb.w*qscale;
    }
  }

  for (int kt = 0; kt < 16; kt++) {
    __syncthreads();
    #pragma unroll
    for (int i = 0; i < 4; i++) {
      int idx = tid + i * 256;          // 0..1023
      int r = idx >> 4, c4 = idx & 15;
      const float* kp = base + (size_t)(kt * 64 + r) * (3 * DIM) + c4 * 4;
      *(float4*)&ks[r][c4 * 4] = *(const float4*)(kp + DIM);
      *(float4*)&vs[r][c4 * 4] = *(const float4*)(kp + 2 * DIM);
    }
    __syncthreads();

    #pragma unroll 2
    for (int jj = 0; jj < 32; jj++) {
      int j = khalf * 32 + jj;
      float4 k0v = *(const float4*)&ks[j][dpart];
      float4 k1v = *(const float4*)&ks[j][dpart + 4];
      float4 k2v = *(const float4*)&ks[j][dpart + 8];
      float4 k3v = *(const float4*)&ks[j][dpart + 12];
      float kr[16] = {k0v.x,k0v.y,k0v.z,k0v.w, k1v.x,k1v.y,k1v.z,k1v.w,
                      k2v.x,k2v.y,k2v.z,k2v.w, k3v.x,k3v.y,k3v.z,k3v.w};
      float sA = 0.f, sB = 0.f;
      #pragma unroll
      for (int d = 0; d < 16; d++) {
        sA = fmaf(qA[d], kr[d], sA);
        sB = fmaf(qB[d], kr[d], sB);
      }
      sA += __shfl_xor(sA, 1);  sB += __shfl_xor(sB, 1);
      sA += __shfl_xor(sA, 2);  sB += __shfl_xor(sB, 2);
      float pA = exp2f(sA);
      float pB = exp2f(sB);
      lA += pA;  lB += pB;
      float4 v0v = *(const float4*)&vs[j][dpart];
      float4 v1v = *(const float4*)&vs[j][dpart + 4];
      float4 v2v = *(const float4*)&vs[j][dpart + 8];
      float4 v3v = *(const float4*)&vs[j][dpart + 12];
      float vr[16] = {v0v.x,v0v.y,v0v.z,v0v.w, v1v.x,v1v.y,v1v.z,v1v.w,
                      v2v.x,v2v.y,v2v.z,v2v.w, v3v.x,v3v.y,v3v.z,v3v.w};
      #pragma unroll
      for (int d = 0; d < 16; d++) {
        accA[d] = fmaf(pA, vr[d], accA[d]);
        accB[d] = fmaf(pB, vr[d], accB[d]);
      }
    }
  }

  // combine khalf=1 partials into khalf=0, normalize, store
  __syncthreads();
  if (khalf == 1) {
    #pragma unroll
    for (int d4 = 0; d4 < 4; d4++) {
      *(float4*)&ks[q0][dpart + d4*4] =
          make_float4(accA[d4*4], accA[d4*4+1], accA[d4*4+2], accA[d4*4+3]);
      *(float4*)&ks[q0 + 1][dpart + d4*4] =
          make_float4(accB[d4*4], accB[d4*4+1], accB[d4*4+2], accB[d4*4+3]);
    }
    if (sub == 0) { vs[0][q0] = lA; vs[0][q0 + 1] = lB; }
  }
  __syncthreads();
  if (khalf == 0) {
    lA += vs[0][q0];
    lB += vs[0][q0 + 1];
    float invA = 1.f / lA, invB = 1.f / lB;
    float* opA = ctx + ((size_t)b * 1024 + qt * 64 + q0) * DIM + h * 64 + dpart;
    float* opB = opA + DIM;
    #pragma unroll
    for (int d4 = 0; d4 < 4; d4++) {
      float4 ca = *(const float4*)&ks[q0][dpart + d4*4];
      float4 cb = *(const float4*)&ks[q0 + 1][dpart + d4*4];
      float4 oa, ob;
      oa.x = (accA[d4*4+0] + ca.x) * invA;
      oa.y = (accA[d4*4+1] + ca.y) * invA;
      oa.z = (accA[d4*4+2] + ca.z) * invA;
      oa.w = (accA[d4*4+3] + ca.w) * invA;
      ob.x = (accB[d4*4+0] + cb.x) * invB;
      ob.y = (accB[d4*4+1] + cb.y) * invB;
      ob.z = (accB[d4*4+2] + cb.z) * invB;
      ob.w = (accB[d4*4+3] + cb.w) * invB;
      *(float4*)(opA + d4 * 4) = oa;
      *(float4*)(opB + d4 * 4) = ob;
    }
  }
}

// ---------------- router ----------------
__global__ __launch_bounds__(256) void router_kernel(
    const float* __restrict__ y, const float* __restrict__ wr,
    float* __restrict__ probs, int* __restrict__ topi,
    float* __restrict__ topg, int* __restrict__ counts)
{
  __shared__ float w[DIM * NEXP];
  const int tid = threadIdx.x;
  for (int i = tid; i < DIM * NEXP; i += 256) w[i] = wr[i];
  __syncthreads();

  const int t = blockIdx.x * 256 + tid;
  const float* yp = y + (size_t)t * DIM;
  float logit[8] = {};
  for (int d = 0; d < DIM; d++) {
    float xv = yp[d];
    #pragma unroll
    for (int e = 0; e < 8; e++) logit[e] = fmaf(xv, w[d * 8 + e], logit[e]);
  }
  float mx = logit[0];
  #pragma unroll
  for (int e = 1; e < 8; e++) mx = fmaxf(mx, logit[e]);
  float p[8], sum = 0.f;
  #pragma unroll
  for (int e = 0; e < 8; e++) { p[e] = __expf(logit[e] - mx); sum += p[e]; }
  float inv = 1.f / sum;
  #pragma unroll
  for (int e = 0; e < 8; e++) { p[e] *= inv; probs[(size_t)t * 8 + e] = p[e]; }

  int i0 = 0;
  #pragma unroll
  for (int e = 1; e < 8; e++) if (p[e] > p[i0]) i0 = e;
  int i1 = (i0 == 0) ? 1 : 0;
  #pragma unroll
  for (int e = 0; e < 8; e++) if (e != i0 && p[e] > p[i1]) i1 = e;
  float g = p[i0] + p[i1];
  topi[2 * t] = i0;  topi[2 * t + 1] = i1;
  topg[2 * t] = p[i0] / g;  topg[2 * t + 1] = p[i1] / g;
  atomicAdd(&counts[i0], 1);
  atomicAdd(&counts[i1], 1);
}

__global__ void init_meta(int* counts) {
  if (threadIdx.x < 8) counts[threadIdx.x] = 0;
}

__global__ void scan_kernel(const int* __restrict__ counts,
                            int* __restrict__ offsets, int* __restrict__ cursors) {
  if (threadIdx.x == 0) {
    int s = 0;
    for (int e = 0; e < 8; e++) { offsets[e] = s; cursors[e] = s; s += counts[e]; }
    offsets[8] = s;
  }
}

__global__ __launch_bounds__(256) void scatter_kernel(
    const int* __restrict__ topi, const float* __restrict__ topg,
    int* __restrict__ cursors, int* __restrict__ perm, float* __restrict__ gperm)
{
  const int t = blockIdx.x * 256 + threadIdx.x;
  #pragma unroll
  for (int s = 0; s < 2; s++) {
    int e = topi[2 * t + s];
    int pos = atomicAdd(&cursors[e], 1);
    perm[pos] = t;
    gperm[pos] = topg[2 * t + s];
  }
}

// ---------------- launch ----------------
extern "C" void kernel_launch(void* const* d_in, const int* in_sizes, int n_in,
                              void* d_out, int out_size, void* d_ws, size_t ws_size,
                              hipStream_t stream) {
  const float* x        = (const float*)d_in[0];
  const float* w_qkv    = (const float*)d_in[1];
  const float* b_qkv    = (const float*)d_in[2];
  const float* w_o      = (const float*)d_in[3];
  const float* b_o      = (const float*)d_in[4];
  const float* w_router = (const float*)d_in[5];
  const float* w1       = (const float*)d_in[6];
  const float* b1       = (const float*)d_in[7];
  const float* w2       = (const float*)d_in[8];
  const float* b2       = (const float*)d_in[9];

  float* out   = (float*)d_out;
  float* probs = out + (size_t)T_TOK * DIM;

  char* ws = (char*)d_ws;
  float* qkv  = (float*)ws;                  // union with hbuf
  short* hbuf = (short*)ws;
  short* wT   = (short*)(ws + 50331648);
  float* ctx  = (float*)(ws + 88080384);
  float* y    = (float*)(ws + 100663296);
  char*  meta = ws + 113246208;
  int*   counts  = (int*)meta;
  int*   cursors = counts + 8;
  int*   offsets = cursors + 8;
  int*   topi    = offsets + 16;
  float* topg    = (float*)(topi + 8192);
  int*   perm    = (int*)(topg + 8192);
  float* gperm   = (float*)(perm + 8192);

  hipMemsetAsync(d_out, 0, (size_t)out_size * sizeof(float), stream);
  init_meta<<<1, 64, 0, stream>>>(counts);

  // QKV (fp32): [4096,768] @ [768,2304]
  gemm_f32<128, 64><<<dim3((3 * DIM) / 64, T_TOK / 128), 256, 0, stream>>>(
      x, w_qkv, b_qkv, qkv, T_TOK, 3 * DIM, DIM);

  attn_kernel<<<dim3(16, 48), 256, 0, stream>>>(qkv, ctx);

  // output proj (fp32): [4096,768] @ [768,768]
  gemm_f32<64, 64><<<dim3(DIM / 64, T_TOK / 64), 256, 0, stream>>>(
      ctx, w_o, b_o, y, T_TOK, DIM, DIM);

  router_kernel<<<16, 256, 0, stream>>>(y, w_router, probs, topi, topg, counts);
  scan_kernel<<<1, 64, 0, stream>>>(counts, offsets, cursors);
  scatter_kernel<<<16, 256, 0, stream>>>(topi, topg, cursors, perm, gperm);

  transpose_bf16<<<dim3(FDIM / 32, DIM / 32, NEXP), dim3(32, 8), 0, stream>>>(
      w1, wT, DIM, FDIM);
  moe_mfma<1><<<dim3(FDIM / 128, T_TOK / 128, NEXP), 256, 0, stream>>>(
      y, wT, b1, hbuf, FDIM, DIM, offsets, perm, gperm);
  transpose_bf16<<<dim3(DIM / 32, FDIM / 32, NEXP), dim3(32, 8), 0, stream>>>(
      w2, wT, FDIM, DIM);
  moe_mfma<2><<<dim3(DIM / 128, T_TOK / 128, NEXP), 256, 0, stream>>>(
      hbuf, wT, b2, out, DIM, FDIM, offsets, perm, gperm);
}

// Round 4
// 1137.721 us; speedup vs baseline: 5.4378x; 1.1158x over previous
//
#include <hip/hip_runtime.h>
#include <hip/hip_bf16.h>
#include <cstdint>
#include <cmath>

#define T_TOK 4096
#define DIM   768
#define HEADS 12
#define HD    64
#define NEXP  8
#define FDIM  3072

typedef __attribute__((ext_vector_type(8))) short short8v;
typedef __attribute__((ext_vector_type(4))) float float4v;

__device__ __forceinline__ float gelu_tanh(float x) {
  // matches jax.nn.gelu(approximate=True)
  float u = 0.7978845608028654f * (x + 0.044715f * x * x * x);
  return 0.5f * x * (1.0f + tanhf(u));
}

__device__ __forceinline__ short f2bf(float x) {
  __hip_bfloat16 h = __float2bfloat16(x);
  return *reinterpret_cast<short*>(&h);
}

// ---------------- fp32 tiled GEMM (attention path only: QKV, o-proj) --------
template<int TBM, int TBN>
__global__ __launch_bounds__(256) void gemm_f32(
    const float* __restrict__ A, const float* __restrict__ W,
    const float* __restrict__ bias, float* __restrict__ C,
    int M, int N, int K)
{
  constexpr int MM = TBM / 16;
  constexpr int MN = TBN / 16;
  constexpr int ALOAD = TBM * 16 / 256;
  constexpr int BLOAD = TBN * 16 / 256;
  __shared__ float As[16][TBM + 4];
  __shared__ float Bs[16][TBN + 4];
  const int bm = blockIdx.y * TBM;
  const int bn = blockIdx.x * TBN;
  const int tid = threadIdx.x;
  const int tr = tid >> 4;
  const int tc = tid & 15;

  float acc[MM][MN] = {};

  for (int k0 = 0; k0 < K; k0 += 16) {
    #pragma unroll
    for (int i = 0; i < ALOAD; i++) {
      int idx = tid + i * 256;
      int m  = idx >> 4;
      int kk = idx & 15;
      As[kk][m] = A[(size_t)(bm + m) * K + k0 + kk];
    }
    #pragma unroll
    for (int i = 0; i < BLOAD; i++) {
      int idx = tid + i * 256;
      int kk = idx / TBN;
      int n  = idx % TBN;
      Bs[kk][n] = W[(size_t)(k0 + kk) * N + bn + n];
    }
    __syncthreads();
    #pragma unroll
    for (int kk = 0; kk < 16; kk++) {
      float a[MM], b[MN];
      #pragma unroll
      for (int u4 = 0; u4 < MM / 4; u4++) {
        float4 t = *(const float4*)&As[kk][tr * MM + u4 * 4];
        a[u4*4+0]=t.x; a[u4*4+1]=t.y; a[u4*4+2]=t.z; a[u4*4+3]=t.w;
      }
      #pragma unroll
      for (int v4 = 0; v4 < MN / 4; v4++) {
        float4 t = *(const float4*)&Bs[kk][tc * MN + v4 * 4];
        b[v4*4+0]=t.x; b[v4*4+1]=t.y; b[v4*4+2]=t.z; b[v4*4+3]=t.w;
      }
      #pragma unroll
      for (int u = 0; u < MM; u++)
        #pragma unroll
        for (int v = 0; v < MN; v++)
          acc[u][v] = fmaf(a[u], b[v], acc[u][v]);
    }
    __syncthreads();
  }

  #pragma unroll
  for (int u = 0; u < MM; u++) {
    int row = bm + tr * MM + u;
    #pragma unroll
    for (int v4 = 0; v4 < MN / 4; v4++) {
      int col = bn + tc * MN + v4 * 4;
      float4 o;
      o.x = acc[u][v4*4+0] + bias[col+0];
      o.y = acc[u][v4*4+1] + bias[col+1];
      o.z = acc[u][v4*4+2] + bias[col+2];
      o.w = acc[u][v4*4+3] + bias[col+3];
      *(float4*)&C[(size_t)row * N + col] = o;
    }
  }
}

// ---------------- transpose + fp32->bf16 convert: W[K][N] -> WT[N][K] -------
__global__ __launch_bounds__(256) void transpose_bf16(
    const float* __restrict__ W, short* __restrict__ WT, int K, int N)
{
  __shared__ float t[32][33];
  const size_t mat = (size_t)K * N;
  const float* Wp = W + blockIdx.z * mat;
  short* WTp = WT + blockIdx.z * mat;
  int n0 = blockIdx.x * 32, k0 = blockIdx.y * 32;
  int tx = threadIdx.x, ty = threadIdx.y;  // 32 x 8
  #pragma unroll
  for (int i = 0; i < 4; i++)
    t[ty + i * 8][tx] = Wp[(size_t)(k0 + ty + i * 8) * N + n0 + tx];
  __syncthreads();
  #pragma unroll
  for (int i = 0; i < 4; i++)
    WTp[(size_t)(n0 + ty + i * 8) * K + k0 + tx] = f2bf(t[tx][ty + i * 8]);
}

// ---------------- y fp32 -> bf16 --------------------------------------------
__global__ __launch_bounds__(256) void y2bf_kernel(
    const float* __restrict__ y, short* __restrict__ ybf)
{
  int g = blockIdx.x * 256 + threadIdx.x;   // 786432 threads
  float4 v = *(const float4*)&y[(size_t)g * 4];
  short4 s = make_short4(f2bf(v.x), f2bf(v.y), f2bf(v.z), f2bf(v.w));
  *(short4*)&ybf[(size_t)g * 4] = s;
}

// ---------------- MoE up-proj: hbuf = gelu(gather(ybf)@W1T^T + b1) ----------
// 128x128 tile, BK=32, 4 waves (2x2), 16x16x32 MFMA, 4x4 frags.
__global__ __launch_bounds__(256) void moe_up(
    const short* __restrict__ ybf, const short* __restrict__ WT,
    const float* __restrict__ bias, short* __restrict__ hbuf,
    const int* __restrict__ offsets, const int* __restrict__ perm)
{
  const int e = blockIdx.z;
  const int start = offsets[e];
  const int M = offsets[e + 1] - start;
  const int bm = blockIdx.y * 128;
  if (bm >= M) return;
  const int bn = blockIdx.x * 128;

  __shared__ short As[4][128][8];
  __shared__ short Bs[4][128][8];
  __shared__ int   perm_s[128];

  const int tid  = threadIdx.x;
  const int lane = tid & 63;
  const int wave = tid >> 6;
  const int wm = wave >> 1, wn = wave & 1;
  const int lr = lane & 15;
  const int kb = lane >> 4;

  const short* WTe = WT + (size_t)e * ((size_t)FDIM * DIM);
  const float* be  = bias + (size_t)e * FDIM;

  if (tid < 128) {
    int rr = bm + tid;
    perm_s[tid] = (rr < M) ? perm[start + rr] : perm[start];
  }
  __syncthreads();

  const int q = tid & 3;
  const int mrow = tid >> 2;                 // 0..63
  const short* aptr[2];
  const short* bptr[2];
  #pragma unroll
  for (int i = 0; i < 2; i++) {
    aptr[i] = ybf + (size_t)perm_s[mrow + i * 64] * DIM;
    bptr[i] = WTe + (size_t)(bn + mrow + i * 64) * DIM;
  }

  float4v acc[4][4] = {};

  for (int k0 = 0; k0 < DIM; k0 += 32) {
    int4 av[2], bv[2];
    #pragma unroll
    for (int i = 0; i < 2; i++) {
      av[i] = *(const int4*)(aptr[i] + k0 + q * 8);
      bv[i] = *(const int4*)(bptr[i] + k0 + q * 8);
    }
    __syncthreads();
    #pragma unroll
    for (int i = 0; i < 2; i++) {
      *(int4*)&As[q][mrow + i * 64][0] = av[i];
      *(int4*)&Bs[q][mrow + i * 64][0] = bv[i];
    }
    __syncthreads();

    short8v af[4], bfv[4];
    #pragma unroll
    for (int mi = 0; mi < 4; mi++)
      af[mi] = *(const short8v*)&As[kb][wm * 64 + mi * 16 + lr][0];
    #pragma unroll
    for (int ni = 0; ni < 4; ni++)
      bfv[ni] = *(const short8v*)&Bs[kb][wn * 64 + ni * 16 + lr][0];
    #pragma unroll
    for (int mi = 0; mi < 4; mi++)
      #pragma unroll
      for (int ni = 0; ni < 4; ni++)
        acc[mi][ni] = __builtin_amdgcn_mfma_f32_16x16x32_bf16(
            af[mi], bfv[ni], acc[mi][ni], 0, 0, 0);
  }

  // D mapping: col = lane&15, row = (lane>>4)*4 + reg
  #pragma unroll
  for (int ni = 0; ni < 4; ni++) {
    int col = bn + wn * 64 + ni * 16 + lr;
    float b = be[col];
    #pragma unroll
    for (int mi = 0; mi < 4; mi++) {
      int lrow0 = wm * 64 + mi * 16 + kb * 4;
      #pragma unroll
      for (int r = 0; r < 4; r++) {
        int rr = bm + lrow0 + r;
        if (rr < M)
          hbuf[(size_t)(start + rr) * FDIM + col] = f2bf(gelu_tanh(acc[mi][ni][r] + b));
      }
    }
  }
}

// ---------------- MoE down-proj: oe = hbuf@W2T^T + b2 (dense rows) ----------
// 64x128 tile, BK=32, 4 waves (1x4), 4x2 frags. No atomics, no gather.
__global__ __launch_bounds__(256) void moe_down(
    const short* __restrict__ hbuf, const short* __restrict__ WT,
    const float* __restrict__ bias, float* __restrict__ oe,
    const int* __restrict__ offsets)
{
  const int e = blockIdx.z;
  const int start = offsets[e];
  const int M = offsets[e + 1] - start;
  const int bm = blockIdx.y * 64;
  if (bm >= M) return;
  const int bn = blockIdx.x * 128;

  __shared__ short As[4][64][8];
  __shared__ short Bs[4][128][8];

  const int tid  = threadIdx.x;
  const int lane = tid & 63;
  const int wn   = tid >> 6;        // wave 0..3, covers cols wn*32..wn*32+31
  const int lr   = lane & 15;
  const int kb   = lane >> 4;

  const short* WTe = WT + (size_t)e * ((size_t)DIM * FDIM);
  const float* be  = bias + (size_t)e * DIM;

  const int q = tid & 3;
  const int mrow = tid >> 2;        // 0..63
  int rr0 = bm + mrow; if (rr0 >= M) rr0 = M - 1;
  const short* aptr = hbuf + (size_t)(start + rr0) * FDIM;
  const short* bptr[2];
  #pragma unroll
  for (int i = 0; i < 2; i++)
    bptr[i] = WTe + (size_t)(bn + mrow + i * 64) * FDIM;

  float4v acc[4][2] = {};

  for (int k0 = 0; k0 < FDIM; k0 += 32) {
    int4 av = *(const int4*)(aptr + k0 + q * 8);
    int4 bv[2];
    #pragma unroll
    for (int i = 0; i < 2; i++) bv[i] = *(const int4*)(bptr[i] + k0 + q * 8);
    __syncthreads();
    *(int4*)&As[q][mrow][0] = av;
    #pragma unroll
    for (int i = 0; i < 2; i++) *(int4*)&Bs[q][mrow + i * 64][0] = bv[i];
    __syncthreads();

    short8v af[4], bfv[2];
    #pragma unroll
    for (int mi = 0; mi < 4; mi++)
      af[mi] = *(const short8v*)&As[kb][mi * 16 + lr][0];
    #pragma unroll
    for (int ni = 0; ni < 2; ni++)
      bfv[ni] = *(const short8v*)&Bs[kb][wn * 32 + ni * 16 + lr][0];
    #pragma unroll
    for (int mi = 0; mi < 4; mi++)
      #pragma unroll
      for (int ni = 0; ni < 2; ni++)
        acc[mi][ni] = __builtin_amdgcn_mfma_f32_16x16x32_bf16(
            af[mi], bfv[ni], acc[mi][ni], 0, 0, 0);
  }

  #pragma unroll
  for (int ni = 0; ni < 2; ni++) {
    int col = bn + wn * 32 + ni * 16 + lr;
    float b = be[col];
    #pragma unroll
    for (int mi = 0; mi < 4; mi++) {
      #pragma unroll
      for (int r = 0; r < 4; r++) {
        int rr = bm + mi * 16 + kb * 4 + r;
        if (rr < M)
          oe[(size_t)(start + rr) * DIM + col] = acc[mi][ni][r] + b;
      }
    }
  }
}

// ---------------- combine: out[t] = g0*oe[p0] + g1*oe[p1] -------------------
__global__ __launch_bounds__(256) void combine_kernel(
    const float* __restrict__ oe, const int* __restrict__ ppos,
    const float* __restrict__ topg, float* __restrict__ out)
{
  int g = blockIdx.x * 256 + threadIdx.x;    // 4096*192 threads
  int t = g / 192;
  int c = (g - t * 192) * 4;
  int p0 = ppos[2 * t], p1 = ppos[2 * t + 1];
  float g0 = topg[2 * t], g1 = topg[2 * t + 1];
  float4 a = *(const float4*)&oe[(size_t)p0 * DIM + c];
  float4 b = *(const float4*)&oe[(size_t)p1 * DIM + c];
  float4 o;
  o.x = g0 * a.x + g1 * b.x;
  o.y = g0 * a.y + g1 * b.y;
  o.z = g0 * a.z + g1 * b.z;
  o.w = g0 * a.w + g1 * b.w;
  *(float4*)&out[(size_t)t * DIM + c] = o;
}

// ---------------- attention (fp32, no-max softmax, key-split waves) --------
__global__ __launch_bounds__(256) void attn_kernel(
    const float* __restrict__ qkv, float* __restrict__ ctx)
{
  const int qt = blockIdx.x;
  const int bh = blockIdx.y;
  const int b = bh / HEADS, h = bh % HEADS;
  const float* base = qkv + (size_t)b * 1024 * (3 * DIM) + h * 64;

  __shared__ float ks[64][64];
  __shared__ float vs[64][64];

  const int tid   = threadIdx.x;
  const int wv    = tid >> 6;
  const int qhalf = wv & 1;
  const int khalf = wv >> 1;
  const int lane  = tid & 63;
  const int grp   = lane >> 2;
  const int sub   = lane & 3;
  const int q0    = qhalf * 32 + grp * 2;
  const int dpart = sub * 16;

  const float qscale = 0.125f * 1.44269504088896f;
  float qA[16], qB[16], accA[16] = {}, accB[16] = {};
  float lA = 0.f, lB = 0.f;

  {
    const float* qpA = base + (size_t)(qt * 64 + q0) * (3 * DIM) + dpart;
    const float* qpB = qpA + 3 * DIM;
    #pragma unroll
    for (int d4 = 0; d4 < 4; d4++) {
      float4 ta = *(const float4*)(qpA + d4 * 4);
      float4 tb = *(const float4*)(qpB + d4 * 4);
      qA[d4*4+0]=ta.x*qscale; qA[d4*4+1]=ta.y*qscale; qA[d4*4+2]=ta.z*qscale; qA[d4*4+3]=ta.w*qscale;
      qB[d4*4+0]=tb.x*qscale; qB[d4*4+1]=tb.y*qscale; qB[d4*4+2]=tb.z*qscale; qB[d4*4+3]=tb.w*qscale;
    }
  }

  for (int kt = 0; kt < 16; kt++) {
    __syncthreads();
    #pragma unroll
    for (int i = 0; i < 4; i++) {
      int idx = tid + i * 256;
      int r = idx >> 4, c4 = idx & 15;
      const float* kp = base + (size_t)(kt * 64 + r) * (3 * DIM) + c4 * 4;
      *(float4*)&ks[r][c4 * 4] = *(const float4*)(kp + DIM);
      *(float4*)&vs[r][c4 * 4] = *(const float4*)(kp + 2 * DIM);
    }
    __syncthreads();

    #pragma unroll 2
    for (int jj = 0; jj < 32; jj++) {
      int j = khalf * 32 + jj;
      float4 k0v = *(const float4*)&ks[j][dpart];
      float4 k1v = *(const float4*)&ks[j][dpart + 4];
      float4 k2v = *(const float4*)&ks[j][dpart + 8];
      float4 k3v = *(const float4*)&ks[j][dpart + 12];
      float kr[16] = {k0v.x,k0v.y,k0v.z,k0v.w, k1v.x,k1v.y,k1v.z,k1v.w,
                      k2v.x,k2v.y,k2v.z,k2v.w, k3v.x,k3v.y,k3v.z,k3v.w};
      float sA = 0.f, sB = 0.f;
      #pragma unroll
      for (int d = 0; d < 16; d++) {
        sA = fmaf(qA[d], kr[d], sA);
        sB = fmaf(qB[d], kr[d], sB);
      }
      sA += __shfl_xor(sA, 1);  sB += __shfl_xor(sB, 1);
      sA += __shfl_xor(sA, 2);  sB += __shfl_xor(sB, 2);
      float pA = exp2f(sA);
      float pB = exp2f(sB);
      lA += pA;  lB += pB;
      float4 v0v = *(const float4*)&vs[j][dpart];
      float4 v1v = *(const float4*)&vs[j][dpart + 4];
      float4 v2v = *(const float4*)&vs[j][dpart + 8];
      float4 v3v = *(const float4*)&vs[j][dpart + 12];
      float vr[16] = {v0v.x,v0v.y,v0v.z,v0v.w, v1v.x,v1v.y,v1v.z,v1v.w,
                      v2v.x,v2v.y,v2v.z,v2v.w, v3v.x,v3v.y,v3v.z,v3v.w};
      #pragma unroll
      for (int d = 0; d < 16; d++) {
        accA[d] = fmaf(pA, vr[d], accA[d]);
        accB[d] = fmaf(pB, vr[d], accB[d]);
      }
    }
  }

  __syncthreads();
  if (khalf == 1) {
    #pragma unroll
    for (int d4 = 0; d4 < 4; d4++) {
      *(float4*)&ks[q0][dpart + d4*4] =
          make_float4(accA[d4*4], accA[d4*4+1], accA[d4*4+2], accA[d4*4+3]);
      *(float4*)&ks[q0 + 1][dpart + d4*4] =
          make_float4(accB[d4*4], accB[d4*4+1], accB[d4*4+2], accB[d4*4+3]);
    }
    if (sub == 0) { vs[0][q0] = lA; vs[0][q0 + 1] = lB; }
  }
  __syncthreads();
  if (khalf == 0) {
    lA += vs[0][q0];
    lB += vs[0][q0 + 1];
    float invA = 1.f / lA, invB = 1.f / lB;
    float* opA = ctx + ((size_t)b * 1024 + qt * 64 + q0) * DIM + h * 64 + dpart;
    float* opB = opA + DIM;
    #pragma unroll
    for (int d4 = 0; d4 < 4; d4++) {
      float4 ca = *(const float4*)&ks[q0][dpart + d4*4];
      float4 cb = *(const float4*)&ks[q0 + 1][dpart + d4*4];
      float4 oa, ob;
      oa.x = (accA[d4*4+0] + ca.x) * invA;
      oa.y = (accA[d4*4+1] + ca.y) * invA;
      oa.z = (accA[d4*4+2] + ca.z) * invA;
      oa.w = (accA[d4*4+3] + ca.w) * invA;
      ob.x = (accB[d4*4+0] + cb.x) * invB;
      ob.y = (accB[d4*4+1] + cb.y) * invB;
      ob.z = (accB[d4*4+2] + cb.z) * invB;
      ob.w = (accB[d4*4+3] + cb.w) * invB;
      *(float4*)(opA + d4 * 4) = oa;
      *(float4*)(opB + d4 * 4) = ob;
    }
  }
}

// ---------------- router ----------------
__global__ __launch_bounds__(256) void router_kernel(
    const float* __restrict__ y, const float* __restrict__ wr,
    float* __restrict__ probs, int* __restrict__ topi,
    float* __restrict__ topg, int* __restrict__ counts)
{
  __shared__ float w[DIM * NEXP];
  const int tid = threadIdx.x;
  for (int i = tid; i < DIM * NEXP; i += 256) w[i] = wr[i];
  __syncthreads();

  const int t = blockIdx.x * 256 + tid;
  const float* yp = y + (size_t)t * DIM;
  float logit[8] = {};
  for (int d = 0; d < DIM; d++) {
    float xv = yp[d];
    #pragma unroll
    for (int e = 0; e < 8; e++) logit[e] = fmaf(xv, w[d * 8 + e], logit[e]);
  }
  float mx = logit[0];
  #pragma unroll
  for (int e = 1; e < 8; e++) mx = fmaxf(mx, logit[e]);
  float p[8], sum = 0.f;
  #pragma unroll
  for (int e = 0; e < 8; e++) { p[e] = __expf(logit[e] - mx); sum += p[e]; }
  float inv = 1.f / sum;
  #pragma unroll
  for (int e = 0; e < 8; e++) { p[e] *= inv; probs[(size_t)t * 8 + e] = p[e]; }

  int i0 = 0;
  #pragma unroll
  for (int e = 1; e < 8; e++) if (p[e] > p[i0]) i0 = e;
  int i1 = (i0 == 0) ? 1 : 0;
  #pragma unroll
  for (int e = 0; e < 8; e++) if (e != i0 && p[e] > p[i1]) i1 = e;
  float g = p[i0] + p[i1];
  topi[2 * t] = i0;  topi[2 * t + 1] = i1;
  topg[2 * t] = p[i0] / g;  topg[2 * t + 1] = p[i1] / g;
  atomicAdd(&counts[i0], 1);
  atomicAdd(&counts[i1], 1);
}

__global__ void init_meta(int* counts) {
  if (threadIdx.x < 8) counts[threadIdx.x] = 0;
}

__global__ void scan_kernel(const int* __restrict__ counts,
                            int* __restrict__ offsets, int* __restrict__ cursors) {
  if (threadIdx.x == 0) {
    int s = 0;
    for (int e = 0; e < 8; e++) { offsets[e] = s; cursors[e] = s; s += counts[e]; }
    offsets[8] = s;
  }
}

__global__ __launch_bounds__(256) void scatter_kernel(
    const int* __restrict__ topi, int* __restrict__ cursors,
    int* __restrict__ perm, int* __restrict__ ppos)
{
  const int t = blockIdx.x * 256 + threadIdx.x;
  #pragma unroll
  for (int s = 0; s < 2; s++) {
    int e = topi[2 * t + s];
    int pos = atomicAdd(&cursors[e], 1);
    perm[pos] = t;
    ppos[2 * t + s] = pos;
  }
}

// ---------------- launch ----------------
extern "C" void kernel_launch(void* const* d_in, const int* in_sizes, int n_in,
                              void* d_out, int out_size, void* d_ws, size_t ws_size,
                              hipStream_t stream) {
  const float* x        = (const float*)d_in[0];
  const float* w_qkv    = (const float*)d_in[1];
  const float* b_qkv    = (const float*)d_in[2];
  const float* w_o      = (const float*)d_in[3];
  const float* b_o      = (const float*)d_in[4];
  const float* w_router = (const float*)d_in[5];
  const float* w1       = (const float*)d_in[6];
  const float* b1       = (const float*)d_in[7];
  const float* w2       = (const float*)d_in[8];
  const float* b2       = (const float*)d_in[9];

  float* out   = (float*)d_out;
  float* probs = out + (size_t)T_TOK * DIM;

  char* ws = (char*)d_ws;
  // region A [0, 50331648): qkv f32 (37.75MB) -> hbuf bf16 (50.33MB)
  float* qkv  = (float*)ws;
  short* hbuf = (short*)ws;
  // wT [50331648, 88080384)
  short* wT   = (short*)(ws + 50331648);
  // region C [88080384, 113246208): ctx f32 | later ybf bf16 | later oe f32
  float* ctx  = (float*)(ws + 88080384);
  short* ybf  = (short*)(ws + 88080384);
  float* oe   = (float*)(ws + 88080384);
  float* y    = (float*)(ws + 100663296);
  char*  meta = ws + 113246208;
  int*   counts  = (int*)meta;
  int*   cursors = counts + 8;
  int*   offsets = cursors + 8;
  int*   topi    = offsets + 16;
  float* topg    = (float*)(topi + 8192);
  int*   perm    = (int*)(topg + 8192);
  int*   ppos    = perm + 8192;

  init_meta<<<1, 64, 0, stream>>>(counts);

  // QKV (fp32): [4096,768] @ [768,2304]
  gemm_f32<128, 64><<<dim3((3 * DIM) / 64, T_TOK / 128), 256, 0, stream>>>(
      x, w_qkv, b_qkv, qkv, T_TOK, 3 * DIM, DIM);

  attn_kernel<<<dim3(16, 48), 256, 0, stream>>>(qkv, ctx);

  // output proj (fp32): [4096,768] @ [768,768]
  gemm_f32<64, 64><<<dim3(DIM / 64, T_TOK / 64), 256, 0, stream>>>(
      ctx, w_o, b_o, y, T_TOK, DIM, DIM);

  router_kernel<<<16, 256, 0, stream>>>(y, w_router, probs, topi, topg, counts);
  scan_kernel<<<1, 64, 0, stream>>>(counts, offsets, cursors);
  scatter_kernel<<<16, 256, 0, stream>>>(topi, cursors, perm, ppos);

  // y -> bf16 (once; up-proj gathers duplicated rows from this)
  y2bf_kernel<<<(T_TOK * DIM / 4) / 256, 256, 0, stream>>>(y, ybf);

  // w1 [8][768][3072] -> w1t bf16 [8][3072][768]
  transpose_bf16<<<dim3(FDIM / 32, DIM / 32, NEXP), dim3(32, 8), 0, stream>>>(
      w1, wT, DIM, FDIM);
  moe_up<<<dim3(FDIM / 128, T_TOK / 128, NEXP), 256, 0, stream>>>(
      ybf, wT, b1, hbuf, offsets, perm);

  // w2 [8][3072][768] -> w2t bf16 [8][768][3072]
  transpose_bf16<<<dim3(DIM / 32, FDIM / 32, NEXP), dim3(32, 8), 0, stream>>>(
      w2, wT, FDIM, DIM);
  moe_down<<<dim3(DIM / 128, T_TOK / 64, NEXP), 256, 0, stream>>>(
      hbuf, wT, b2, oe, offsets);

  combine_kernel<<<(T_TOK * DIM / 4) / 256, 256, 0, stream>>>(oe, ppos, topg, out);
}